// Round 5
// baseline (120.061 us; speedup 1.0000x reference)
//
#include <hip/hip_runtime.h>

#define BD 8
#define SD 64
#define CD 3
#define HD 224
#define WD 224
#define ED 128
#define PD 16
#define HWD (HD*WD)
#define KD (CD*PD*PD)   /* 768 */
#define PRT 8           /* partitions per (b,c) for the hierarchical scatter */
#define CHK (HWD/PRT)   /* 6272 pixels per partition */
#define IG 4            /* i's (segments) amortized per k_out block */

typedef float v2f __attribute__((ext_vector_type(2)));

// All buffers fp32. Scratch in module globals; every byte fully overwritten
// each call, no global atomics (R9/R10/R11 history). Timed-region model (R18):
// 2x 256MiB harness poison fills (~82us, untouchable) + kernels+gaps (~37us).
// k_labels theory: LDS-ISSUE-bound (896 broadcast ds_read_b64/wave x 24.5
// waves/CU x ~2-4cyc on the shared per-CU LDS pipe ~= 18-36us >> 5us VALU
// floor; explains R2 pair-pack neutrality: same LDS count). R18 change:
// quad-pack weights as float4 rows -> ds_read_b128 broadcast, 448 LDS
// inst/wave (half). Logits bit-identical (same bias-init + j-order FMA).
// R19: identical resubmit -- R18 bench was an infra failure (container), not
// a kernel failure; the quad-pack A/B measurement is still pending.
__device__ float              g_part[BD * CD * PRT * SD * 256];  // 12.6 MB partials
__device__ int                g_labels[BD * HWD];
__device__ unsigned long long g_ppres[BD * PRT];                 // presence per (b,part)

// Kernel 1: 3x3 SAME conv -> argmax(64ch) -> labels.
// LDS layout: row q (q=0..15) = channels 4q..4q+3: 27 float4 weight quads
// (w[4q+0][j], w[4q+1][j], w[4q+2][j], w[4q+3][j]) + bias quad at slot 27.
// Inner loop: 1 broadcast ds_read_b128 per tap, 2 pk-FMA (channel pairs
// 01 / 23), 4 ordered strict-> compares = jnp first-max argmax.
__global__ __launch_bounds__(256) void k_labels(
    const float* __restrict__ img,
    const float* __restrict__ wsp,
    const float* __restrict__ bsp)
{
    __shared__ __align__(16) float4 w_s[16 * 28];   // 7 KB
    const int tid = threadIdx.x;
    for (int t = tid; t < 16 * 28; t += 256) {
        const int q = t / 28, j = t - q * 28;
        float4 v;
        if (j < 27) {
            v.x = wsp[(4 * q + 0) * 27 + j];
            v.y = wsp[(4 * q + 1) * 27 + j];
            v.z = wsp[(4 * q + 2) * 27 + j];
            v.w = wsp[(4 * q + 3) * 27 + j];
        } else {
            v.x = bsp[4 * q + 0]; v.y = bsp[4 * q + 1];
            v.z = bsp[4 * q + 2]; v.w = bsp[4 * q + 3];
        }
        w_s[t] = v;
    }
    __syncthreads();

    const int p = blockIdx.x * 256 + tid;
    const int b = blockIdx.y;
    const int h = p / WD;
    const int w = p - h * WD;

    const float* ib = img + (size_t)b * CD * HWD;
    v2f pd[27];                                   // pixel duplicated into both halves
    #pragma unroll
    for (int c = 0; c < 3; ++c)
        #pragma unroll
        for (int dh = 0; dh < 3; ++dh)
            #pragma unroll
            for (int dw = 0; dw < 3; ++dw) {
                int hh = h + dh - 1, ww = w + dw - 1;
                bool ok = (hh >= 0) & (hh < HD) & (ww >= 0) & (ww < WD);
                const float val = ok ? ib[c * HWD + hh * WD + ww] : 0.f;
                const int j = (c * 3 + dh) * 3 + dw;
                pd[j].x = val; pd[j].y = val;
            }

    float best = -INFINITY;
    int bi = 0;
    for (int q = 0; q < 16; ++q) {
        const float4* wrow = w_s + q * 28;        // same addr all lanes -> broadcast
        const float4 bq = wrow[27];
        v2f a01 = { bq.x, bq.y };
        v2f a23 = { bq.z, bq.w };
        #pragma unroll
        for (int j = 0; j < 27; ++j) {
            const float4 wv = wrow[j];            // one ds_read_b128 per tap
            const v2f w01 = { wv.x, wv.y };
            const v2f w23 = { wv.z, wv.w };
            a01 = __builtin_elementwise_fma(pd[j], w01, a01);
            a23 = __builtin_elementwise_fma(pd[j], w23, a23);
        }
        if (a01.x > best) { best = a01.x; bi = 4 * q;     }   // strict > = first max
        if (a01.y > best) { best = a01.y; bi = 4 * q + 1; }
        if (a23.x > best) { best = a23.x; bi = 4 * q + 2; }
        if (a23.y > best) { best = a23.y; bi = 4 * q + 3; }
    }
    g_labels[b * HWD + p] = bi;
}

// Kernel 2: hierarchical scatter. Block = (partition, channel, batch); owns a
// 6272-pixel chunk, accumulates into a 64KB LDS table [lab][cell] via LDS
// atomics, writes its partial table exclusively (coalesced). Cell = patch-tap
// index ((h&15)<<4|(w&15)) -- MUST match wp's (dh,dw) layout, not an arbitrary
// partition. int4/float4 loads, 4 aligned pixels per group (rows %4==0 so
// groups never split; base+3 stays in-row). Unchanged from R17 (measured).
__global__ __launch_bounds__(256) void k_hist(const float* __restrict__ img)
{
    const int part = blockIdx.x, c = blockIdx.y, b = blockIdx.z;
    const int tid = threadIdx.x;

    __shared__ float acc[SD * 256];            // 64 KB
    __shared__ unsigned long long pm;
    #pragma unroll
    for (int k = 0; k < 16; ++k)
        ((float4*)acc)[k * 256 + tid] = make_float4(0.f, 0.f, 0.f, 0.f);
    if (tid == 0) pm = 0ull;
    __syncthreads();

    const int start = part * CHK;
    const int*   lb = g_labels + (size_t)b * HWD;
    const float* ic = img + ((size_t)b * CD + c) * HWD;

    unsigned long long m = 0ull;

    #define HIST_GROUP(g)                                                  \
    {                                                                      \
        const int p4 = start + (g) * 4;                                    \
        const int4   l4 = *(const int4*)(lb + p4);                         \
        const float4 v4 = *(const float4*)(ic + p4);                       \
        const int h = p4 / WD;                                             \
        const int w0 = p4 - h * WD;                                        \
        const int base = ((h & 15) << 4) | (w0 & 15);                      \
        atomicAdd(&acc[l4.x * 256 + base + 0], v4.x);                      \
        atomicAdd(&acc[l4.y * 256 + base + 1], v4.y);                      \
        atomicAdd(&acc[l4.z * 256 + base + 2], v4.z);                      \
        atomicAdd(&acc[l4.w * 256 + base + 3], v4.w);                      \
        m |= 1ull << l4.x; m |= 1ull << l4.y;                              \
        m |= 1ull << l4.z; m |= 1ull << l4.w;                              \
    }

    #pragma unroll
    for (int it = 0; it < 6; ++it) HIST_GROUP(tid + it * 256);  // 6*256 = 1536 groups
    if (tid < (CHK / 4 - 6 * 256)) HIST_GROUP(tid + 6 * 256);   // tail: 32 groups
    #undef HIST_GROUP

    #pragma unroll
    for (int d = 1; d < 64; d <<= 1) m |= __shfl_xor(m, d, 64);
    if ((tid & 63) == 0) atomicOr(&pm, m);
    __syncthreads();

    float4* dst = (float4*)(g_part + (((size_t)(b * CD + c)) * PRT + part) * (SD * 256));
    #pragma unroll
    for (int k = 0; k < 16; ++k)
        dst[k * 256 + tid] = ((float4*)acc)[k * 256 + tid];
    if (c == 0 && tid == 0) g_ppres[b * PRT + part] = pm;
}

// Kernel 3: out[b,i,e] = bias[e] + (1/196)*dot(G[b,uniq(b,i),:], wp[e,:]).
// IG=4 segments per block, 4-way e-split -> grid (16,8,4) = 512 blocks.
// Each wp e-row load feeds 4 dots (wp L2 traffic 197MB -> 49MB). Unchanged
// from R17 (measured, -2.2us).
__global__ __launch_bounds__(256) void k_out(
    const float* __restrict__ wp,
    const float* __restrict__ bp,
    float* __restrict__ out)
{
    __shared__ float4 gs4[IG][KD / 4];         // 4 x 192 float4 = 12 KB
    const int ig = blockIdx.x;                 // i group: i = ig*4 .. ig*4+3
    const int b = blockIdx.y;
    const int z = blockIdx.z;                  // e base = z*32
    const int tid = threadIdx.x;
    const int lane = tid & 63;
    const int wv = tid >> 6;

    unsigned long long m = 0ull;
    #pragma unroll
    for (int p2 = 0; p2 < PRT; ++p2) m |= g_ppres[b * PRT + p2];  // uniform -> s_load
    const int nu = __popcll(m);

    int ls[IG];
    #pragma unroll
    for (int ii = 0; ii < IG; ++ii) {
        const int i = ig * IG + ii;
        int l = 0;
        if (i < nu) {
            unsigned long long mm = m;
            for (int t = 0; t < i; ++t) mm &= mm - 1;   // clear i lowest set bits
            l = __builtin_ctzll(mm);                    // i-th smallest label
        }
        ls[ii] = l;                                     // pad -> 0, matches jnp pad
    }

    // merge PRT partials for 4 labels: 768 float4 slots, 3 per thread
    #pragma unroll
    for (int k = 0; k < 3; ++k) {
        const int t = tid + k * 256;
        const int ii_ = t / 192, idx = t - ii_ * 192;
        const int c = idx >> 6, cell4 = idx & 63;
        const float4* src = (const float4*)g_part
            + ((size_t)(b * CD + c) * PRT) * 4096 + ls[ii_] * 64 + cell4;
        float4 s = src[0];
        #pragma unroll
        for (int p2 = 1; p2 < PRT; ++p2) {
            float4 v = src[(size_t)p2 * 4096];
            s.x += v.x; s.y += v.y; s.z += v.z; s.w += v.w;
        }
        gs4[ii_][idx] = s;
    }
    __syncthreads();

    float4 G[IG][3];
    #pragma unroll
    for (int ii = 0; ii < IG; ++ii) {
        G[ii][0] = gs4[ii][lane];
        G[ii][1] = gs4[ii][lane + 64];
        G[ii][2] = gs4[ii][lane + 128];
    }

    #pragma unroll 2
    for (int j = 0; j < 8; ++j) {
        const int e = z * 32 + wv * 8 + j;
        const float4* wr = (const float4*)(wp + (size_t)e * KD);
        const float4 a0 = wr[lane], a1 = wr[lane + 64], a2 = wr[lane + 128];
        float acc[IG];
        #pragma unroll
        for (int ii = 0; ii < IG; ++ii) {
            float t = G[ii][0].x * a0.x;
            t = fmaf(G[ii][0].y, a0.y, t); t = fmaf(G[ii][0].z, a0.z, t);
            t = fmaf(G[ii][0].w, a0.w, t);
            t = fmaf(G[ii][1].x, a1.x, t); t = fmaf(G[ii][1].y, a1.y, t);
            t = fmaf(G[ii][1].z, a1.z, t); t = fmaf(G[ii][1].w, a1.w, t);
            t = fmaf(G[ii][2].x, a2.x, t); t = fmaf(G[ii][2].y, a2.y, t);
            t = fmaf(G[ii][2].z, a2.z, t); t = fmaf(G[ii][2].w, a2.w, t);
            acc[ii] = t;
        }
        #pragma unroll
        for (int off = 32; off; off >>= 1) {
            #pragma unroll
            for (int ii = 0; ii < IG; ++ii) acc[ii] += __shfl_xor(acc[ii], off, 64);
        }
        if (lane == 0) {
            #pragma unroll
            for (int ii = 0; ii < IG; ++ii)
                out[(size_t)(b * SD + ig * IG + ii) * ED + e] = bp[e] + acc[ii] * (1.f / 196.f);
        }
    }
}

extern "C" void kernel_launch(void* const* d_in, const int* in_sizes, int n_in,
                              void* d_out, int out_size, void* d_ws, size_t ws_size,
                              hipStream_t stream) {
    const float *img = nullptr, *wsp = nullptr, *bsp = nullptr, *wp = nullptr, *bp = nullptr;
    for (int i = 0; i < n_in; ++i) {
        switch (in_sizes[i]) {
            case BD * CD * HWD:      img = (const float*)d_in[i]; break;  // 1204224
            case SD * CD * 9:        wsp = (const float*)d_in[i]; break;  // 1728
            case SD:                 bsp = (const float*)d_in[i]; break;  // 64
            case ED * CD * PD * PD:  wp  = (const float*)d_in[i]; break;  // 98304
            case ED:                 bp  = (const float*)d_in[i]; break;  // 128
        }
    }
    float* out = (float*)d_out;

    dim3 g1(HWD / 256, BD, 1);
    k_labels<<<g1, 256, 0, stream>>>(img, wsp, bsp);

    dim3 g2(PRT, CD, BD);
    k_hist<<<g2, 256, 0, stream>>>(img);

    dim3 g3(SD / IG, BD, 4);
    k_out<<<g3, 256, 0, stream>>>(wp, bp, out);
}

// Round 6
// 114.687 us; speedup vs baseline: 1.0469x; 1.0469x over previous
//
#include <hip/hip_runtime.h>

#define BD 8
#define SD 64
#define CD 3
#define HD 224
#define WD 224
#define ED 128
#define PD 16
#define HWD (HD*WD)
#define KD (CD*PD*PD)   /* 768 */
#define PRT 8           /* partitions per (b,c) for the hierarchical scatter */
#define CHK (HWD/PRT)   /* 6272 pixels per partition */
#define IG 4            /* i's (segments) amortized per k_out block */

typedef float v2f __attribute__((ext_vector_type(2)));

// All buffers fp32. Scratch in module globals; fully overwritten each call; no
// global atomics. Timed-region model (R20): 2x 256MiB poison fills (~82us,
// untouchable) + kernels+gaps (~38us). k_labels model v3: LDS cost is
// DELIVERED-DWORD-proportional (register return path ~1 wave-reg/cyc): 1792
// weight dwords/wave x 24.5 waves/CU ~= 18us. Evidence: R2 (pair-pack, same
// dwords) null on k_labels, R5 (b64->b128, half instr, same dwords) NULL.
// R20 change: PIX=2 -- two vertical pixels/thread, weight quads read once per
// PAIR -> 896 dwords/pixel (half), img loads 27->18/pixel. VALU/pixel and
// per-channel FMA order unchanged (logits bit-identical).
__device__ float              g_part[BD * CD * PRT * SD * 256];  // 12.6 MB partials
__device__ int                g_labels[BD * HWD];
__device__ unsigned long long g_ppres[BD * PRT];                 // presence per (b,part)

// Kernel 1: 3x3 SAME conv -> argmax(64ch) -> labels, 2 pixels per thread.
// LDS: row q (q=0..15) = channels 4q..4q+3: 27 float4 weight quads + bias quad
// at slot 27. Inner: 1 broadcast ds_read_b128 per tap per PAIR, 4 pk-FMA
// (2 per pixel), 8 ordered strict-> compares = jnp first-max argmax.
__global__ __launch_bounds__(256) void k_labels(
    const float* __restrict__ img,
    const float* __restrict__ wsp,
    const float* __restrict__ bsp)
{
    __shared__ __align__(16) float4 w_s[16 * 28];   // 7 KB
    const int tid = threadIdx.x;
    for (int t = tid; t < 16 * 28; t += 256) {
        const int q = t / 28, j = t - q * 28;
        float4 v;
        if (j < 27) {
            v.x = wsp[(4 * q + 0) * 27 + j];
            v.y = wsp[(4 * q + 1) * 27 + j];
            v.z = wsp[(4 * q + 2) * 27 + j];
            v.w = wsp[(4 * q + 3) * 27 + j];
        } else {
            v.x = bsp[4 * q + 0]; v.y = bsp[4 * q + 1];
            v.z = bsp[4 * q + 2]; v.w = bsp[4 * q + 3];
        }
        w_s[t] = v;
    }
    __syncthreads();

    const int pp = blockIdx.x * 256 + tid;        // pixel-pair index in batch
    const int b = blockIdx.y;
    const int hp = pp / WD;                       // 0..111
    const int w  = pp - hp * WD;
    const int hA = 2 * hp;                        // pixel A row; B = hA+1

    const float* ib = img + (size_t)b * CD * HWD;
    // window rows hA-1 .. hA+2 (4 rows) x cols w-1..w+1 x 3 ch = 36 loads.
    // pdA taps use rows r=0..2, pdB taps rows r=1..3 (duplicated v2f halves).
    v2f pdA[27], pdB[27];
    #pragma unroll
    for (int c = 0; c < 3; ++c)
        #pragma unroll
        for (int r = 0; r < 4; ++r)
            #pragma unroll
            for (int dw = 0; dw < 3; ++dw) {
                const int hh = hA - 1 + r, ww = w + dw - 1;
                const bool ok = (hh >= 0) & (hh < HD) & (ww >= 0) & (ww < WD);
                const float val = ok ? ib[c * HWD + hh * WD + ww] : 0.f;
                if (r < 3) {
                    const int j = (c * 3 + r) * 3 + dw;
                    pdA[j].x = val; pdA[j].y = val;
                }
                if (r >= 1) {
                    const int j = (c * 3 + (r - 1)) * 3 + dw;
                    pdB[j].x = val; pdB[j].y = val;
                }
            }

    float bestA = -INFINITY, bestB = -INFINITY;
    int biA = 0, biB = 0;
    for (int q = 0; q < 16; ++q) {
        const float4* wrow = w_s + q * 28;        // same addr all lanes -> broadcast
        const float4 bq = wrow[27];
        v2f aA01 = { bq.x, bq.y }, aA23 = { bq.z, bq.w };
        v2f aB01 = { bq.x, bq.y }, aB23 = { bq.z, bq.w };
        #pragma unroll
        for (int j = 0; j < 27; ++j) {
            const float4 wv = wrow[j];            // one ds_read_b128 per tap per PAIR
            const v2f w01 = { wv.x, wv.y };
            const v2f w23 = { wv.z, wv.w };
            aA01 = __builtin_elementwise_fma(pdA[j], w01, aA01);
            aA23 = __builtin_elementwise_fma(pdA[j], w23, aA23);
            aB01 = __builtin_elementwise_fma(pdB[j], w01, aB01);
            aB23 = __builtin_elementwise_fma(pdB[j], w23, aB23);
        }
        if (aA01.x > bestA) { bestA = aA01.x; biA = 4 * q;     }  // strict > = first max
        if (aA01.y > bestA) { bestA = aA01.y; biA = 4 * q + 1; }
        if (aA23.x > bestA) { bestA = aA23.x; biA = 4 * q + 2; }
        if (aA23.y > bestA) { bestA = aA23.y; biA = 4 * q + 3; }
        if (aB01.x > bestB) { bestB = aB01.x; biB = 4 * q;     }
        if (aB01.y > bestB) { bestB = aB01.y; biB = 4 * q + 1; }
        if (aB23.x > bestB) { bestB = aB23.x; biB = 4 * q + 2; }
        if (aB23.y > bestB) { bestB = aB23.y; biB = 4 * q + 3; }
    }
    g_labels[b * HWD + hA * WD + w]       = biA;
    g_labels[b * HWD + (hA + 1) * WD + w] = biB;
}

// Kernel 2: hierarchical scatter. Block = (partition, channel, batch); owns a
// 6272-pixel chunk, accumulates into a 64KB LDS table [lab][cell] via LDS
// atomics, writes its partial table exclusively (coalesced). Cell = patch-tap
// index ((h&15)<<4|(w&15)) -- MUST match wp's (dh,dw) layout. int4/float4
// loads, 4 aligned pixels per group (rows %4==0 so groups never split).
// Unchanged from R17 (measured).
__global__ __launch_bounds__(256) void k_hist(const float* __restrict__ img)
{
    const int part = blockIdx.x, c = blockIdx.y, b = blockIdx.z;
    const int tid = threadIdx.x;

    __shared__ float acc[SD * 256];            // 64 KB
    __shared__ unsigned long long pm;
    #pragma unroll
    for (int k = 0; k < 16; ++k)
        ((float4*)acc)[k * 256 + tid] = make_float4(0.f, 0.f, 0.f, 0.f);
    if (tid == 0) pm = 0ull;
    __syncthreads();

    const int start = part * CHK;
    const int*   lb = g_labels + (size_t)b * HWD;
    const float* ic = img + ((size_t)b * CD + c) * HWD;

    unsigned long long m = 0ull;

    #define HIST_GROUP(g)                                                  \
    {                                                                      \
        const int p4 = start + (g) * 4;                                    \
        const int4   l4 = *(const int4*)(lb + p4);                         \
        const float4 v4 = *(const float4*)(ic + p4);                       \
        const int h = p4 / WD;                                             \
        const int w0 = p4 - h * WD;                                        \
        const int base = ((h & 15) << 4) | (w0 & 15);                      \
        atomicAdd(&acc[l4.x * 256 + base + 0], v4.x);                      \
        atomicAdd(&acc[l4.y * 256 + base + 1], v4.y);                      \
        atomicAdd(&acc[l4.z * 256 + base + 2], v4.z);                      \
        atomicAdd(&acc[l4.w * 256 + base + 3], v4.w);                      \
        m |= 1ull << l4.x; m |= 1ull << l4.y;                              \
        m |= 1ull << l4.z; m |= 1ull << l4.w;                              \
    }

    #pragma unroll
    for (int it = 0; it < 6; ++it) HIST_GROUP(tid + it * 256);  // 6*256 = 1536 groups
    if (tid < (CHK / 4 - 6 * 256)) HIST_GROUP(tid + 6 * 256);   // tail: 32 groups
    #undef HIST_GROUP

    #pragma unroll
    for (int d = 1; d < 64; d <<= 1) m |= __shfl_xor(m, d, 64);
    if ((tid & 63) == 0) atomicOr(&pm, m);
    __syncthreads();

    float4* dst = (float4*)(g_part + (((size_t)(b * CD + c)) * PRT + part) * (SD * 256));
    #pragma unroll
    for (int k = 0; k < 16; ++k)
        dst[k * 256 + tid] = ((float4*)acc)[k * 256 + tid];
    if (c == 0 && tid == 0) g_ppres[b * PRT + part] = pm;
}

// Kernel 3: out[b,i,e] = bias[e] + (1/196)*dot(G[b,uniq(b,i),:], wp[e,:]).
// IG=4 segments per block, 4-way e-split -> grid (16,8,4) = 512 blocks.
// Each wp e-row load feeds 4 dots (wp L2 traffic 197MB -> 49MB). Unchanged
// from R17 (measured).
__global__ __launch_bounds__(256) void k_out(
    const float* __restrict__ wp,
    const float* __restrict__ bp,
    float* __restrict__ out)
{
    __shared__ float4 gs4[IG][KD / 4];         // 4 x 192 float4 = 12 KB
    const int ig = blockIdx.x;                 // i group: i = ig*4 .. ig*4+3
    const int b = blockIdx.y;
    const int z = blockIdx.z;                  // e base = z*32
    const int tid = threadIdx.x;
    const int lane = tid & 63;
    const int wv = tid >> 6;

    unsigned long long m = 0ull;
    #pragma unroll
    for (int p2 = 0; p2 < PRT; ++p2) m |= g_ppres[b * PRT + p2];  // uniform -> s_load
    const int nu = __popcll(m);

    int ls[IG];
    #pragma unroll
    for (int ii = 0; ii < IG; ++ii) {
        const int i = ig * IG + ii;
        int l = 0;
        if (i < nu) {
            unsigned long long mm = m;
            for (int t = 0; t < i; ++t) mm &= mm - 1;   // clear i lowest set bits
            l = __builtin_ctzll(mm);                    // i-th smallest label
        }
        ls[ii] = l;                                     // pad -> 0, matches jnp pad
    }

    // merge PRT partials for 4 labels: 768 float4 slots, 3 per thread
    #pragma unroll
    for (int k = 0; k < 3; ++k) {
        const int t = tid + k * 256;
        const int ii_ = t / 192, idx = t - ii_ * 192;
        const int c = idx >> 6, cell4 = idx & 63;
        const float4* src = (const float4*)g_part
            + ((size_t)(b * CD + c) * PRT) * 4096 + ls[ii_] * 64 + cell4;
        float4 s = src[0];
        #pragma unroll
        for (int p2 = 1; p2 < PRT; ++p2) {
            float4 v = src[(size_t)p2 * 4096];
            s.x += v.x; s.y += v.y; s.z += v.z; s.w += v.w;
        }
        gs4[ii_][idx] = s;
    }
    __syncthreads();

    float4 G[IG][3];
    #pragma unroll
    for (int ii = 0; ii < IG; ++ii) {
        G[ii][0] = gs4[ii][lane];
        G[ii][1] = gs4[ii][lane + 64];
        G[ii][2] = gs4[ii][lane + 128];
    }

    #pragma unroll 2
    for (int j = 0; j < 8; ++j) {
        const int e = z * 32 + wv * 8 + j;
        const float4* wr = (const float4*)(wp + (size_t)e * KD);
        const float4 a0 = wr[lane], a1 = wr[lane + 64], a2 = wr[lane + 128];
        float acc[IG];
        #pragma unroll
        for (int ii = 0; ii < IG; ++ii) {
            float t = G[ii][0].x * a0.x;
            t = fmaf(G[ii][0].y, a0.y, t); t = fmaf(G[ii][0].z, a0.z, t);
            t = fmaf(G[ii][0].w, a0.w, t);
            t = fmaf(G[ii][1].x, a1.x, t); t = fmaf(G[ii][1].y, a1.y, t);
            t = fmaf(G[ii][1].z, a1.z, t); t = fmaf(G[ii][1].w, a1.w, t);
            t = fmaf(G[ii][2].x, a2.x, t); t = fmaf(G[ii][2].y, a2.y, t);
            t = fmaf(G[ii][2].w, a2.w, t); t = fmaf(G[ii][2].z, a2.z, t);
            acc[ii] = t;
        }
        #pragma unroll
        for (int off = 32; off; off >>= 1) {
            #pragma unroll
            for (int ii = 0; ii < IG; ++ii) acc[ii] += __shfl_xor(acc[ii], off, 64);
        }
        if (lane == 0) {
            #pragma unroll
            for (int ii = 0; ii < IG; ++ii)
                out[(size_t)(b * SD + ig * IG + ii) * ED + e] = bp[e] + acc[ii] * (1.f / 196.f);
        }
    }
}

extern "C" void kernel_launch(void* const* d_in, const int* in_sizes, int n_in,
                              void* d_out, int out_size, void* d_ws, size_t ws_size,
                              hipStream_t stream) {
    const float *img = nullptr, *wsp = nullptr, *bsp = nullptr, *wp = nullptr, *bp = nullptr;
    for (int i = 0; i < n_in; ++i) {
        switch (in_sizes[i]) {
            case BD * CD * HWD:      img = (const float*)d_in[i]; break;  // 1204224
            case SD * CD * 9:        wsp = (const float*)d_in[i]; break;  // 1728
            case SD:                 bsp = (const float*)d_in[i]; break;  // 64
            case ED * CD * PD * PD:  wp  = (const float*)d_in[i]; break;  // 98304
            case ED:                 bp  = (const float*)d_in[i]; break;  // 128
        }
    }
    float* out = (float*)d_out;

    dim3 g1(HWD / 512, BD, 1);   // 2 pixels per thread (vertical pair)
    k_labels<<<g1, 256, 0, stream>>>(img, wsp, bsp);

    dim3 g2(PRT, CD, BD);
    k_hist<<<g2, 256, 0, stream>>>(img);

    dim3 g3(SD / IG, BD, 4);
    k_out<<<g3, 256, 0, stream>>>(wp, bp, out);
}

// Round 7
// 113.888 us; speedup vs baseline: 1.0542x; 1.0070x over previous
//
#include <hip/hip_runtime.h>

#define BD 8
#define SD 64
#define CD 3
#define HD 224
#define WD 224
#define ED 128
#define PD 16
#define HWD (HD*WD)
#define KD (CD*PD*PD)   /* 768 */
#define PRT 8           /* partitions per (b,c) for the hierarchical scatter */
#define CHK (HWD/PRT)   /* 6272 pixels per partition */
#define IG 4            /* i's (segments) amortized per k_out block */

typedef float v2f __attribute__((ext_vector_type(2)));

// All buffers fp32. Scratch in module globals; fully overwritten each call; no
// global atomics. Timed-region model (R21): 2x 256MiB poison fills (~82us,
// untouchable) + kernels+gaps (~33us). k_labels model v3 CONFIRMED by R6 A/B:
// LDS cost is DELIVERED-DWORD-proportional (return path 256B/clk/CU = 64
// dwords/cyc); R2/R5 (same dwords) null, R6 (PIX=2, half dwords) -5.4us.
// R21: PIX=4 vertical pixels/thread -> 7 weight-dwords/pixel (half of PIX=2).
// Pixel regs PAIR-PACKED: pAB=(pixA,pixB), pCD=(pixC,pixD) (108 VGPR, not
// 216); weight splat {w,w} at use site (VOP3P op_sel; worst case v_mov).
// Per-channel FMA chain order unchanged -> logits bit-identical.
__device__ float              g_part[BD * CD * PRT * SD * 256];  // 12.6 MB partials
__device__ int                g_labels[BD * HWD];
__device__ unsigned long long g_ppres[BD * PRT];                 // presence per (b,part)

// Kernel 1: 3x3 SAME conv -> argmax(64ch) -> labels, 4 vertical pixels/thread.
// LDS: row q (q=0..15) = channels 4q..4q+3: 27 float4 weight quads + bias quad
// at slot 27. Inner: 1 broadcast ds_read_b128 per tap per 4 PIXELS, 8 pk-FMA
// (4ch x 2 pixel-pairs), 16 ordered strict-> compares = jnp first-max argmax.
__global__ __launch_bounds__(256) void k_labels(
    const float* __restrict__ img,
    const float* __restrict__ wsp,
    const float* __restrict__ bsp)
{
    __shared__ __align__(16) float4 w_s[16 * 28];   // 7 KB
    const int tid = threadIdx.x;
    for (int t = tid; t < 16 * 28; t += 256) {
        const int q = t / 28, j = t - q * 28;
        float4 v;
        if (j < 27) {
            v.x = wsp[(4 * q + 0) * 27 + j];
            v.y = wsp[(4 * q + 1) * 27 + j];
            v.z = wsp[(4 * q + 2) * 27 + j];
            v.w = wsp[(4 * q + 3) * 27 + j];
        } else {
            v.x = bsp[4 * q + 0]; v.y = bsp[4 * q + 1];
            v.z = bsp[4 * q + 2]; v.w = bsp[4 * q + 3];
        }
        w_s[t] = v;
    }
    __syncthreads();

    const int pp = blockIdx.x * 256 + tid;        // pixel-quad index in batch
    const int b = blockIdx.y;
    const int hp = pp / WD;                       // 0..55
    const int w  = pp - hp * WD;
    const int h0 = 4 * hp;                        // pixels at rows h0..h0+3

    const float* ib = img + (size_t)b * CD * HWD;
    // window rows h0-1 .. h0+4 (6 rows) x cols w-1..w+1 x 3 ch = 54 loads.
    float va[3][6][3];                            // [c][rr][dw], fully static idx
    #pragma unroll
    for (int c = 0; c < 3; ++c)
        #pragma unroll
        for (int rr = 0; rr < 6; ++rr)
            #pragma unroll
            for (int dw = 0; dw < 3; ++dw) {
                const int hh = h0 - 1 + rr, ww = w + dw - 1;
                const bool ok = (hh >= 0) & (hh < HD) & (ww >= 0) & (ww < WD);
                va[c][rr][dw] = ok ? ib[c * HWD + hh * WD + ww] : 0.f;
            }

    // pair-packed taps: pAB[j] = (tap_j of pixel A, tap_j of pixel B), etc.
    v2f pAB[27], pCD[27];
    #pragma unroll
    for (int c = 0; c < 3; ++c)
        #pragma unroll
        for (int dh = 0; dh < 3; ++dh)
            #pragma unroll
            for (int dw = 0; dw < 3; ++dw) {
                const int j = (c * 3 + dh) * 3 + dw;
                pAB[j].x = va[c][dh + 0][dw]; pAB[j].y = va[c][dh + 1][dw];
                pCD[j].x = va[c][dh + 2][dw]; pCD[j].y = va[c][dh + 3][dw];
            }

    float bestA = -INFINITY, bestB = -INFINITY, bestC = -INFINITY, bestD = -INFINITY;
    int biA = 0, biB = 0, biC = 0, biD = 0;
    for (int q = 0; q < 16; ++q) {
        const float4* wrow = w_s + q * 28;        // same addr all lanes -> broadcast
        const float4 bq = wrow[27];
        v2f aAB[4], aCD[4];
        aAB[0] = (v2f){bq.x, bq.x}; aCD[0] = (v2f){bq.x, bq.x};
        aAB[1] = (v2f){bq.y, bq.y}; aCD[1] = (v2f){bq.y, bq.y};
        aAB[2] = (v2f){bq.z, bq.z}; aCD[2] = (v2f){bq.z, bq.z};
        aAB[3] = (v2f){bq.w, bq.w}; aCD[3] = (v2f){bq.w, bq.w};
        #pragma unroll
        for (int j = 0; j < 27; ++j) {
            const float4 wv = wrow[j];            // one ds_read_b128 per tap per QUAD
            const v2f w0 = {wv.x, wv.x}, w1 = {wv.y, wv.y};
            const v2f w2 = {wv.z, wv.z}, w3 = {wv.w, wv.w};
            aAB[0] = __builtin_elementwise_fma(pAB[j], w0, aAB[0]);
            aCD[0] = __builtin_elementwise_fma(pCD[j], w0, aCD[0]);
            aAB[1] = __builtin_elementwise_fma(pAB[j], w1, aAB[1]);
            aCD[1] = __builtin_elementwise_fma(pCD[j], w1, aCD[1]);
            aAB[2] = __builtin_elementwise_fma(pAB[j], w2, aAB[2]);
            aCD[2] = __builtin_elementwise_fma(pCD[j], w2, aCD[2]);
            aAB[3] = __builtin_elementwise_fma(pAB[j], w3, aAB[3]);
            aCD[3] = __builtin_elementwise_fma(pCD[j], w3, aCD[3]);
        }
        #pragma unroll
        for (int k = 0; k < 4; ++k) {             // ch 4q+k ascending, strict > = first max
            if (aAB[k].x > bestA) { bestA = aAB[k].x; biA = 4 * q + k; }
            if (aAB[k].y > bestB) { bestB = aAB[k].y; biB = 4 * q + k; }
            if (aCD[k].x > bestC) { bestC = aCD[k].x; biC = 4 * q + k; }
            if (aCD[k].y > bestD) { bestD = aCD[k].y; biD = 4 * q + k; }
        }
    }
    int* lrow = g_labels + b * HWD + h0 * WD + w;
    lrow[0 * WD] = biA;
    lrow[1 * WD] = biB;
    lrow[2 * WD] = biC;
    lrow[3 * WD] = biD;
}

// Kernel 2: hierarchical scatter. Block = (partition, channel, batch); owns a
// 6272-pixel chunk, accumulates into a 64KB LDS table [lab][cell] via LDS
// atomics, writes its partial table exclusively (coalesced). Cell = patch-tap
// index ((h&15)<<4|(w&15)) -- MUST match wp's (dh,dw) layout. int4/float4
// loads, 4 aligned pixels per group (rows %4==0 so groups never split).
// Unchanged from R17 (measured).
__global__ __launch_bounds__(256) void k_hist(const float* __restrict__ img)
{
    const int part = blockIdx.x, c = blockIdx.y, b = blockIdx.z;
    const int tid = threadIdx.x;

    __shared__ float acc[SD * 256];            // 64 KB
    __shared__ unsigned long long pm;
    #pragma unroll
    for (int k = 0; k < 16; ++k)
        ((float4*)acc)[k * 256 + tid] = make_float4(0.f, 0.f, 0.f, 0.f);
    if (tid == 0) pm = 0ull;
    __syncthreads();

    const int start = part * CHK;
    const int*   lb = g_labels + (size_t)b * HWD;
    const float* ic = img + ((size_t)b * CD + c) * HWD;

    unsigned long long m = 0ull;

    #define HIST_GROUP(g)                                                  \
    {                                                                      \
        const int p4 = start + (g) * 4;                                    \
        const int4   l4 = *(const int4*)(lb + p4);                         \
        const float4 v4 = *(const float4*)(ic + p4);                       \
        const int h = p4 / WD;                                             \
        const int w0 = p4 - h * WD;                                        \
        const int base = ((h & 15) << 4) | (w0 & 15);                      \
        atomicAdd(&acc[l4.x * 256 + base + 0], v4.x);                      \
        atomicAdd(&acc[l4.y * 256 + base + 1], v4.y);                      \
        atomicAdd(&acc[l4.z * 256 + base + 2], v4.z);                      \
        atomicAdd(&acc[l4.w * 256 + base + 3], v4.w);                      \
        m |= 1ull << l4.x; m |= 1ull << l4.y;                              \
        m |= 1ull << l4.z; m |= 1ull << l4.w;                              \
    }

    #pragma unroll
    for (int it = 0; it < 6; ++it) HIST_GROUP(tid + it * 256);  // 6*256 = 1536 groups
    if (tid < (CHK / 4 - 6 * 256)) HIST_GROUP(tid + 6 * 256);   // tail: 32 groups
    #undef HIST_GROUP

    #pragma unroll
    for (int d = 1; d < 64; d <<= 1) m |= __shfl_xor(m, d, 64);
    if ((tid & 63) == 0) atomicOr(&pm, m);
    __syncthreads();

    float4* dst = (float4*)(g_part + (((size_t)(b * CD + c)) * PRT + part) * (SD * 256));
    #pragma unroll
    for (int k = 0; k < 16; ++k)
        dst[k * 256 + tid] = ((float4*)acc)[k * 256 + tid];
    if (c == 0 && tid == 0) g_ppres[b * PRT + part] = pm;
}

// Kernel 3: out[b,i,e] = bias[e] + (1/196)*dot(G[b,uniq(b,i),:], wp[e,:]).
// IG=4 segments per block, 4-way e-split -> grid (16,8,4) = 512 blocks.
// Each wp e-row load feeds 4 dots (wp L2 traffic 197MB -> 49MB). Unchanged
// from R6-measured source.
__global__ __launch_bounds__(256) void k_out(
    const float* __restrict__ wp,
    const float* __restrict__ bp,
    float* __restrict__ out)
{
    __shared__ float4 gs4[IG][KD / 4];         // 4 x 192 float4 = 12 KB
    const int ig = blockIdx.x;                 // i group: i = ig*4 .. ig*4+3
    const int b = blockIdx.y;
    const int z = blockIdx.z;                  // e base = z*32
    const int tid = threadIdx.x;
    const int lane = tid & 63;
    const int wv = tid >> 6;

    unsigned long long m = 0ull;
    #pragma unroll
    for (int p2 = 0; p2 < PRT; ++p2) m |= g_ppres[b * PRT + p2];  // uniform -> s_load
    const int nu = __popcll(m);

    int ls[IG];
    #pragma unroll
    for (int ii = 0; ii < IG; ++ii) {
        const int i = ig * IG + ii;
        int l = 0;
        if (i < nu) {
            unsigned long long mm = m;
            for (int t = 0; t < i; ++t) mm &= mm - 1;   // clear i lowest set bits
            l = __builtin_ctzll(mm);                    // i-th smallest label
        }
        ls[ii] = l;                                     // pad -> 0, matches jnp pad
    }

    // merge PRT partials for 4 labels: 768 float4 slots, 3 per thread
    #pragma unroll
    for (int k = 0; k < 3; ++k) {
        const int t = tid + k * 256;
        const int ii_ = t / 192, idx = t - ii_ * 192;
        const int c = idx >> 6, cell4 = idx & 63;
        const float4* src = (const float4*)g_part
            + ((size_t)(b * CD + c) * PRT) * 4096 + ls[ii_] * 64 + cell4;
        float4 s = src[0];
        #pragma unroll
        for (int p2 = 1; p2 < PRT; ++p2) {
            float4 v = src[(size_t)p2 * 4096];
            s.x += v.x; s.y += v.y; s.z += v.z; s.w += v.w;
        }
        gs4[ii_][idx] = s;
    }
    __syncthreads();

    float4 G[IG][3];
    #pragma unroll
    for (int ii = 0; ii < IG; ++ii) {
        G[ii][0] = gs4[ii][lane];
        G[ii][1] = gs4[ii][lane + 64];
        G[ii][2] = gs4[ii][lane + 128];
    }

    #pragma unroll 2
    for (int j = 0; j < 8; ++j) {
        const int e = z * 32 + wv * 8 + j;
        const float4* wr = (const float4*)(wp + (size_t)e * KD);
        const float4 a0 = wr[lane], a1 = wr[lane + 64], a2 = wr[lane + 128];
        float acc[IG];
        #pragma unroll
        for (int ii = 0; ii < IG; ++ii) {
            float t = G[ii][0].x * a0.x;
            t = fmaf(G[ii][0].y, a0.y, t); t = fmaf(G[ii][0].z, a0.z, t);
            t = fmaf(G[ii][0].w, a0.w, t);
            t = fmaf(G[ii][1].x, a1.x, t); t = fmaf(G[ii][1].y, a1.y, t);
            t = fmaf(G[ii][1].z, a1.z, t); t = fmaf(G[ii][1].w, a1.w, t);
            t = fmaf(G[ii][2].x, a2.x, t); t = fmaf(G[ii][2].y, a2.y, t);
            t = fmaf(G[ii][2].w, a2.w, t); t = fmaf(G[ii][2].z, a2.z, t);
            acc[ii] = t;
        }
        #pragma unroll
        for (int off = 32; off; off >>= 1) {
            #pragma unroll
            for (int ii = 0; ii < IG; ++ii) acc[ii] += __shfl_xor(acc[ii], off, 64);
        }
        if (lane == 0) {
            #pragma unroll
            for (int ii = 0; ii < IG; ++ii)
                out[(size_t)(b * SD + ig * IG + ii) * ED + e] = bp[e] + acc[ii] * (1.f / 196.f);
        }
    }
}

extern "C" void kernel_launch(void* const* d_in, const int* in_sizes, int n_in,
                              void* d_out, int out_size, void* d_ws, size_t ws_size,
                              hipStream_t stream) {
    const float *img = nullptr, *wsp = nullptr, *bsp = nullptr, *wp = nullptr, *bp = nullptr;
    for (int i = 0; i < n_in; ++i) {
        switch (in_sizes[i]) {
            case BD * CD * HWD:      img = (const float*)d_in[i]; break;  // 1204224
            case SD * CD * 9:        wsp = (const float*)d_in[i]; break;  // 1728
            case SD:                 bsp = (const float*)d_in[i]; break;  // 64
            case ED * CD * PD * PD:  wp  = (const float*)d_in[i]; break;  // 98304
            case ED:                 bp  = (const float*)d_in[i]; break;  // 128
        }
    }
    float* out = (float*)d_out;

    dim3 g1(HWD / 1024, BD, 1);   // 4 pixels per thread (vertical quad)
    k_labels<<<g1, 256, 0, stream>>>(img, wsp, bsp);

    dim3 g2(PRT, CD, BD);
    k_hist<<<g2, 256, 0, stream>>>(img);

    dim3 g3(SD / IG, BD, 4);
    k_out<<<g3, 256, 0, stream>>>(wp, bp, out);
}